// Round 5
// baseline (959.313 us; speedup 1.0000x reference)
//
#include <hip/hip_runtime.h>
#include <hip/hip_bf16.h>

#define NTOT  1048576
#define MWG   128          // rows per workgroup
#define BLK   128          // threads (2 waves x 64 rows each)
#define ROWB  384          // act row stride in bytes (192 bf16)
#define ACT_BYTES  (MWG * ROWB)          // 49152

typedef __attribute__((ext_vector_type(8))) short  bf16x8;
typedef __attribute__((ext_vector_type(4))) float  f32x4;

__device__ __forceinline__ unsigned short f2bf(float f) {
  unsigned u = __float_as_uint(f);
  u += 0x7fffu + ((u >> 16) & 1u);          // RNE
  return (unsigned short)(u >> 16);
}

// ---------------- weight prepack ----------------
// fp32 [k][n] (concat-reorder / zero-pad) -> bf16 MFMA-fragment order:
// dst idx = (((nt*KS + ks)*4 + lg)*16 + l15)*8 + e   for n = nt*16+l15, k = ks*32+lg*8+e
__global__ __launch_bounds__(256) void prepack_k(
    const float* __restrict__ s0, const float* __restrict__ s1,
    const float* __restrict__ s2, const float* __restrict__ s3,
    const float* __restrict__ s4, const float* __restrict__ s5,
    const float* __restrict__ s6, const float* __restrict__ s7,
    const float* __restrict__ s8, const float* __restrict__ s9,
    const float* __restrict__ s10, unsigned short* __restrict__ dst)
{
  const int nw_[11]  = {128,128,128,128,128,128,128,128,144, 64, 16};
  const int kw_[11]  = { 64,128,128,128,128,192,128,128,128,192, 64};
  const int nc_[11]  = {128,128,128,128,128,128,128,128,129, 64,  3};
  const int k1_[11]  = { 63,128,128,128,128, 63,128,128,128, 27, 64};
  const int o1_[11]  = {  0,  0,  0,  0,  0,128,  0,  0,  0,128,  0};
  const int k2_[11]  = {999,999,999,999,999, 64,999,999,999, 64,999};
  const int do_[11]  = {0,8192,24576,40960,57344,73728,98304,114688,131072,149504,161792};

  int c = blockIdx.x;
  const float* src =
    c==0?s0: c==1?s1: c==2?s2: c==3?s3: c==4?s4: c==5?s5:
    c==6?s6: c==7?s7: c==8?s8: c==9?s9: s10;
  int nw=nw_[c], kw=kw_[c], nc=nc_[c], k1=k1_[c], o1=o1_[c], k2=k2_[c];
  int KS = kw >> 5;
  int total = nw * kw;
  for (int idx = blockIdx.y * blockDim.x + threadIdx.x; idx < total;
       idx += gridDim.y * blockDim.x) {
    int e   = idx & 7;
    int l15 = (idx >> 3) & 15;
    int lg  = (idx >> 7) & 3;
    int r   = idx >> 9;
    int ks  = r % KS;
    int nt  = r / KS;
    int n = nt * 16 + l15;
    int k = ks * 32 + lg * 8 + e;
    float v = 0.f;
    if (n < nc) {
      if (k < k1)       v = src[(o1 + k) * nc + n];
      else if (k >= k2) v = src[(k - k2) * nc + n];
    }
    dst[do_[c] + idx] = f2bf(v);
  }
}

// ---------------- posenc: 32 cols of one row, all indices compile-time ----------------
template<int I0, int L>
__device__ __forceinline__ void posenc_store(unsigned char* actb, int row,
                                             float p0, float p1, float p2)
{
#pragma unroll
  for (int q = 0; q < 4; q++) {
    unsigned short h[8];
#pragma unroll
    for (int e = 0; e < 8; e++) {
      const int i = I0 + q * 8 + e;
      float v;
      if (i == 0) v = p0;
      else if (i == 1) v = p1;
      else if (i == 2) v = p2;
      else {
        const int idx = i - 3, j = idx / 6, t = idx % 6;
        if (j < L) {
          const float sc = (float)(1 << j);
          const float a  = (t % 3 == 0 ? p0 : (t % 3 == 1 ? p1 : p2)) * sc;
          v = (t < 3) ? __sinf(a) : __cosf(a);
        } else v = 0.f;
      }
      h[e] = f2bf(v);
    }
    uint4 pk;
    pk.x = (unsigned)h[0] | ((unsigned)h[1] << 16);
    pk.y = (unsigned)h[2] | ((unsigned)h[3] << 16);
    pk.z = (unsigned)h[4] | ((unsigned)h[5] << 16);
    pk.w = (unsigned)h[6] | ((unsigned)h[7] << 16);
    int b = (row * ROWB + (I0 + q * 8) * 2) ^ ((row & 7) << 4);
    *(uint4*)(actb + b) = pk;
  }
}

// ---------------- one layer, fully inlined, 64 rows/wave ----------------
// weights from global in fragment order (L2-resident), act in LDS.
// D[n][m] = sum_k Wt[n][k] * act[m][KB+k]
// MODE 0: relu -> act.  MODE 3: no-relu -> act.  MODE 2: sigmoid color -> out.
template<int KS, int NT, int MODE, int KB, int DST>
__device__ __forceinline__ void layer_g(
    unsigned char* actb, const unsigned short* __restrict__ wchunk,
    int mbase, int lane, float* __restrict__ out, long grow0)
{
  const int l15 = lane & 15;
  const int lg  = lane >> 4;
  const unsigned short* wl = wchunk + lane * 8;
  const f32x4 vzero = {0.f, 0.f, 0.f, 0.f};
  f32x4 acc[4][NT];
#pragma unroll
  for (int a = 0; a < 4; a++)
#pragma unroll
    for (int b = 0; b < NT; b++) acc[a][b] = vzero;

#pragma unroll
  for (int ks = 0; ks < KS; ks++) {
    const int kloc = ks * 32 + lg * 8;
    bf16x8 afr[NT];
#pragma unroll
    for (int nt = 0; nt < NT; nt++)
      afr[nt] = *(const bf16x8*)(wl + (nt * KS + ks) * 512);
    bf16x8 bfr[4];
#pragma unroll
    for (int mt = 0; mt < 4; mt++) {
      int m = mbase + mt * 16 + l15;
      int byt = (m * ROWB + (KB + kloc) * 2) ^ ((m & 7) << 4);
      bfr[mt] = *(const bf16x8*)(actb + byt);
    }
#pragma unroll
    for (int nt = 0; nt < NT; nt++)
#pragma unroll
      for (int mt = 0; mt < 4; mt++)
        acc[mt][nt] = __builtin_amdgcn_mfma_f32_16x16x32_bf16(
            afr[nt], bfr[mt], acc[mt][nt], 0, 0, 0);
  }

#pragma unroll
  for (int mt = 0; mt < 4; mt++) {
    int m = mbase + mt * 16 + l15;
#pragma unroll
    for (int nt = 0; nt < NT; nt++) {
      f32x4 v = acc[mt][nt];
      if (MODE == 2) {                   // color, n=0..2 -> lg==0 regs x,y,z
        if (lg == 0) {
          long g3 = (grow0 + m) * 3;
          out[g3 + 0] = 1.f / (1.f + __expf(-v.x));
          out[g3 + 1] = 1.f / (1.f + __expf(-v.y));
          out[g3 + 2] = 1.f / (1.f + __expf(-v.z));
        }
      } else {
        if (MODE == 0) {
          v.x = fmaxf(v.x, 0.f); v.y = fmaxf(v.y, 0.f);
          v.z = fmaxf(v.z, 0.f); v.w = fmaxf(v.w, 0.f);
        }
        unsigned short h0 = f2bf(v.x), h1 = f2bf(v.y), h2 = f2bf(v.z), h3 = f2bf(v.w);
        uint2 pk;
        pk.x = (unsigned)h0 | ((unsigned)h1 << 16);
        pk.y = (unsigned)h2 | ((unsigned)h3 << 16);
        int col = DST + nt * 16 + lg * 4;       // 4 consecutive features, fixed row
        int byt = (m * ROWB + col * 2) ^ ((m & 7) << 4);
        *(uint2*)(actb + byt) = pk;
      }
    }
  }
}

// sigma-only pass: one n-tile (n local 0 -> lg==0 reg x), reads act cols KB..KB+127
template<int KS, int KB>
__device__ __forceinline__ void sigma_g(
    unsigned char* actb, const unsigned short* __restrict__ wchunk,
    int mbase, int lane, float* __restrict__ out, long grow0)
{
  const int l15 = lane & 15;
  const int lg  = lane >> 4;
  const unsigned short* wl = wchunk + lane * 8;
  const f32x4 vzero = {0.f, 0.f, 0.f, 0.f};
  f32x4 acc[4];
#pragma unroll
  for (int a = 0; a < 4; a++) acc[a] = vzero;

#pragma unroll
  for (int ks = 0; ks < KS; ks++) {
    const int kloc = ks * 32 + lg * 8;
    bf16x8 afr = *(const bf16x8*)(wl + ks * 512);
#pragma unroll
    for (int mt = 0; mt < 4; mt++) {
      int m = mbase + mt * 16 + l15;
      int byt = (m * ROWB + (KB + kloc) * 2) ^ ((m & 7) << 4);
      bf16x8 bfr = *(const bf16x8*)(actb + byt);
      acc[mt] = __builtin_amdgcn_mfma_f32_16x16x32_bf16(afr, bfr, acc[mt], 0, 0, 0);
    }
  }
  if (lg == 0) {
#pragma unroll
    for (int mt = 0; mt < 4; mt++) {
      int m = mbase + mt * 16 + l15;
      out[3L * NTOT + grow0 + m] = fmaxf(acc[mt].x, 0.f);
    }
  }
}

__global__ __launch_bounds__(BLK, 2) void nerf_fused(
    const float* __restrict__ pos, const float* __restrict__ dirs,
    const unsigned short* __restrict__ wp, float* __restrict__ out)
{
  __shared__ unsigned char actb[ACT_BYTES];   // act[128][192] bf16, swizzled rows

  const int tid   = threadIdx.x;
  const int lane  = tid & 63;
  const int mbase = (tid >> 6) * 64;          // wave owns 64 rows end-to-end
  const long grow0 = (long)blockIdx.x * MWG;

  const int row = tid;                         // 1 thread = 1 row
  const long g  = grow0 + row;

  // posenc(pos) -> cols 0..62 (col 63 = 0); wave-local, no barrier anywhere
  {
    float p0 = pos[g * 3 + 0], p1 = pos[g * 3 + 1], p2 = pos[g * 3 + 2];
    posenc_store<0, 10>(actb, row, p0, p1, p2);
    posenc_store<32, 10>(actb, row, p0, p1, p2);
  }

  layer_g<2, 8, 0,  0, 64>(actb, wp +      0, mbase, lane, out, grow0);  // b1_w0
  layer_g<4, 8, 0, 64, 64>(actb, wp +   8192, mbase, lane, out, grow0);  // b1_w1
  layer_g<4, 8, 0, 64, 64>(actb, wp +  24576, mbase, lane, out, grow0);  // b1_w2
  layer_g<4, 8, 0, 64, 64>(actb, wp +  40960, mbase, lane, out, grow0);  // b1_w3
  layer_g<4, 8, 0, 64, 64>(actb, wp +  57344, mbase, lane, out, grow0);  // b1_w4
  layer_g<6, 8, 0,  0, 64>(actb, wp +  73728, mbase, lane, out, grow0);  // b2_w0 (K=192)

  // posenc(dirs) -> cols 0..26, 27..63 = 0 (x_emb dead; own rows only)
  {
    float p0 = dirs[g * 3 + 0], p1 = dirs[g * 3 + 1], p2 = dirs[g * 3 + 2];
    posenc_store<0, 4>(actb, row, p0, p1, p2);
    posenc_store<32, 4>(actb, row, p0, p1, p2);   // all zeros
  }

  layer_g<4, 8, 0, 64, 64>(actb, wp +  98304, mbase, lane, out, grow0);  // b2_w1
  layer_g<4, 8, 0, 64, 64>(actb, wp + 114688, mbase, lane, out, grow0);  // b2_w2
  sigma_g<4, 64>          (actb, wp + 147456, mbase, lane, out, grow0);  // sigma (before feat overwrite)
  layer_g<4, 8, 3, 64, 64>(actb, wp + 131072, mbase, lane, out, grow0);  // b2_w3 feat (no relu)
  layer_g<6, 4, 0,  0,  0>(actb, wp + 149504, mbase, lane, out, grow0);  // b3_w0 (K=192) -> cols 0..63
  layer_g<2, 1, 2,  0,  0>(actb, wp + 161792, mbase, lane, out, grow0);  // b3_w1 -> color
}

extern "C" void kernel_launch(void* const* d_in, const int* in_sizes, int n_in,
                              void* d_out, int out_size, void* d_ws, size_t ws_size,
                              hipStream_t stream)
{
  const float* pos  = (const float*)d_in[0];
  const float* dirs = (const float*)d_in[1];
  unsigned short* wpack = (unsigned short*)d_ws;   // 325,632 B used
  float* out = (float*)d_out;

  prepack_k<<<dim3(11, 12, 1), 256, 0, stream>>>(
      (const float*)d_in[2], (const float*)d_in[3], (const float*)d_in[4],
      (const float*)d_in[5], (const float*)d_in[6], (const float*)d_in[7],
      (const float*)d_in[8], (const float*)d_in[9], (const float*)d_in[10],
      (const float*)d_in[11], (const float*)d_in[12], wpack);

  nerf_fused<<<NTOT / MWG, BLK, 0, stream>>>(pos, dirs, wpack, out);
}

// Round 6
// 410.632 us; speedup vs baseline: 2.3362x; 2.3362x over previous
//
#include <hip/hip_runtime.h>
#include <hip/hip_bf16.h>

#define NTOT  1048576
#define MWG   128          // rows per workgroup
#define BLK   256          // threads (4 waves x 32 rows each)
#define ROWB  384          // act row stride in bytes (192 bf16)
#define ACT_BYTES  (MWG * ROWB)          // 49152

typedef __attribute__((ext_vector_type(8))) short  bf16x8;
typedef __attribute__((ext_vector_type(4))) float  f32x4;

__device__ __forceinline__ unsigned short f2bf(float f) {
  unsigned u = __float_as_uint(f);
  u += 0x7fffu + ((u >> 16) & 1u);          // RNE
  return (unsigned short)(u >> 16);
}

__device__ __forceinline__ unsigned pk2bf(float lo, float hi) {
  float2 t; t.x = lo; t.y = hi;
  __hip_bfloat162 b = __float22bfloat162_rn(t);   // RNE, same values as f2bf
  return *(unsigned*)&b;
}

// ---------------- weight prepack ----------------
// fp32 [k][n] (concat-reorder / zero-pad) -> bf16 MFMA-fragment order:
// dst idx = (((nt*KS + ks)*4 + lg)*16 + l15)*8 + e   for n = nt*16+l15, k = ks*32+lg*8+e
__global__ __launch_bounds__(256) void prepack_k(
    const float* __restrict__ s0, const float* __restrict__ s1,
    const float* __restrict__ s2, const float* __restrict__ s3,
    const float* __restrict__ s4, const float* __restrict__ s5,
    const float* __restrict__ s6, const float* __restrict__ s7,
    const float* __restrict__ s8, const float* __restrict__ s9,
    const float* __restrict__ s10, unsigned short* __restrict__ dst)
{
  const int nw_[11]  = {128,128,128,128,128,128,128,128,144, 64, 16};
  const int kw_[11]  = { 64,128,128,128,128,192,128,128,128,192, 64};
  const int nc_[11]  = {128,128,128,128,128,128,128,128,129, 64,  3};
  const int k1_[11]  = { 63,128,128,128,128, 63,128,128,128, 27, 64};
  const int o1_[11]  = {  0,  0,  0,  0,  0,128,  0,  0,  0,128,  0};
  const int k2_[11]  = {999,999,999,999,999, 64,999,999,999, 64,999};
  const int do_[11]  = {0,8192,24576,40960,57344,73728,98304,114688,131072,149504,161792};

  int c = blockIdx.x;
  const float* src =
    c==0?s0: c==1?s1: c==2?s2: c==3?s3: c==4?s4: c==5?s5:
    c==6?s6: c==7?s7: c==8?s8: c==9?s9: s10;
  int nw=nw_[c], kw=kw_[c], nc=nc_[c], k1=k1_[c], o1=o1_[c], k2=k2_[c];
  int KS = kw >> 5;
  int total = nw * kw;
  for (int idx = blockIdx.y * blockDim.x + threadIdx.x; idx < total;
       idx += gridDim.y * blockDim.x) {
    int e   = idx & 7;
    int l15 = (idx >> 3) & 15;
    int lg  = (idx >> 7) & 3;
    int r   = idx >> 9;
    int ks  = r % KS;
    int nt  = r / KS;
    int n = nt * 16 + l15;
    int k = ks * 32 + lg * 8 + e;
    float v = 0.f;
    if (n < nc) {
      if (k < k1)       v = src[(o1 + k) * nc + n];
      else if (k >= k2) v = src[(k - k2) * nc + n];
    }
    dst[do_[c] + idx] = f2bf(v);
  }
}

// ---------------- posenc: 32 cols of one row, all indices compile-time ----------------
template<int I0, int L>
__device__ __forceinline__ void posenc_store(unsigned char* actb, int row,
                                             float p0, float p1, float p2)
{
#pragma unroll
  for (int q = 0; q < 4; q++) {
    float hv[8];
#pragma unroll
    for (int e = 0; e < 8; e++) {
      const int i = I0 + q * 8 + e;
      float v;
      if (i == 0) v = p0;
      else if (i == 1) v = p1;
      else if (i == 2) v = p2;
      else {
        const int idx = i - 3, j = idx / 6, t = idx % 6;
        if (j < L) {
          const float sc = (float)(1 << j);
          const float a  = (t % 3 == 0 ? p0 : (t % 3 == 1 ? p1 : p2)) * sc;
          v = (t < 3) ? __sinf(a) : __cosf(a);
        } else v = 0.f;
      }
      hv[e] = v;
    }
    uint4 pk;
    pk.x = pk2bf(hv[0], hv[1]);
    pk.y = pk2bf(hv[2], hv[3]);
    pk.z = pk2bf(hv[4], hv[5]);
    pk.w = pk2bf(hv[6], hv[7]);
    int b = (row * ROWB + (I0 + q * 8) * 2) ^ ((row & 7) << 4);
    *(uint4*)(actb + b) = pk;
  }
}

// ---------------- one layer, fully inlined, 32 rows/wave ----------------
// weights from global in fragment order (L2-resident), act in LDS.
// D[n][m] = sum_k Wt[n][k] * act[m][KB+k]
// MODE 0: relu -> act.  MODE 1: feat no-relu -> act; nt==8 sigma -> out.  MODE 2: sigmoid color -> out.
template<int KS, int NT, int MODE, int KB, int DST>
__device__ __forceinline__ void layer_g(
    unsigned char* actb, const unsigned short* __restrict__ wchunk,
    int mbase, int lane, float* __restrict__ out, long grow0)
{
  const int l15 = lane & 15;
  const int lg  = lane >> 4;
  const unsigned short* wl = wchunk + lane * 8;
  const f32x4 vzero = {0.f, 0.f, 0.f, 0.f};
  f32x4 acc[2][NT];
#pragma unroll
  for (int a = 0; a < 2; a++)
#pragma unroll
    for (int b = 0; b < NT; b++) acc[a][b] = vzero;

#pragma unroll
  for (int ks = 0; ks < KS; ks++) {
    const int kloc = ks * 32 + lg * 8;
    bf16x8 afr[NT];
#pragma unroll
    for (int nt = 0; nt < NT; nt++)
      afr[nt] = *(const bf16x8*)(wl + (nt * KS + ks) * 512);
    bf16x8 bfr[2];
#pragma unroll
    for (int mt = 0; mt < 2; mt++) {
      int m = mbase + mt * 16 + l15;
      int byt = (m * ROWB + (KB + kloc) * 2) ^ ((m & 7) << 4);
      bfr[mt] = *(const bf16x8*)(actb + byt);
    }
#pragma unroll
    for (int nt = 0; nt < NT; nt++)
#pragma unroll
      for (int mt = 0; mt < 2; mt++)
        acc[mt][nt] = __builtin_amdgcn_mfma_f32_16x16x32_bf16(
            afr[nt], bfr[mt], acc[mt][nt], 0, 0, 0);
  }

#pragma unroll
  for (int mt = 0; mt < 2; mt++) {
    int m = mbase + mt * 16 + l15;
#pragma unroll
    for (int nt = 0; nt < NT; nt++) {
      f32x4 v = acc[mt][nt];
      if (MODE == 1 && nt == 8) {               // sigma (n==128 -> lg==0, reg 0)
        if (lg == 0) out[3L * NTOT + grow0 + m] = fmaxf(v.x, 0.f);
      } else if (MODE == 2) {                   // color, n=0..2 -> lg==0 regs x,y,z
        if (lg == 0) {
          long g3 = (grow0 + m) * 3;
          out[g3 + 0] = 1.f / (1.f + __expf(-v.x));
          out[g3 + 1] = 1.f / (1.f + __expf(-v.y));
          out[g3 + 2] = 1.f / (1.f + __expf(-v.z));
        }
      } else {
        if (MODE == 0) {
          v.x = fmaxf(v.x, 0.f); v.y = fmaxf(v.y, 0.f);
          v.z = fmaxf(v.z, 0.f); v.w = fmaxf(v.w, 0.f);
        }
        uint2 pk;
        pk.x = pk2bf(v.x, v.y);
        pk.y = pk2bf(v.z, v.w);
        int col = DST + nt * 16 + lg * 4;       // 4 consecutive features, fixed row
        int byt = (m * ROWB + col * 2) ^ ((m & 7) << 4);
        *(uint2*)(actb + byt) = pk;
      }
    }
  }
}

__global__ __launch_bounds__(BLK, 3) void nerf_fused(
    const float* __restrict__ pos, const float* __restrict__ dirs,
    const unsigned short* __restrict__ wp, float* __restrict__ out)
{
  __shared__ unsigned char actb[ACT_BYTES];   // act[128][192] bf16, swizzled rows

  const int tid   = threadIdx.x;
  const int lane  = tid & 63;
  const int mbase = (tid >> 6) * 32;          // wave owns 32 rows end-to-end
  const long grow0 = (long)blockIdx.x * MWG;

  const int row = mbase + (lane & 31);
  const long g  = grow0 + row;

  // posenc(pos) -> cols 0..62 (col 63 = 0); wave-local, no barrier anywhere
  {
    float p0 = pos[g * 3 + 0], p1 = pos[g * 3 + 1], p2 = pos[g * 3 + 2];
    if (lane < 32) posenc_store<0, 10>(actb, row, p0, p1, p2);
    else           posenc_store<32, 10>(actb, row, p0, p1, p2);
  }

  layer_g<2, 8, 0,  0, 64>(actb, wp +      0, mbase, lane, out, grow0);  // b1_w0
  layer_g<4, 8, 0, 64, 64>(actb, wp +   8192, mbase, lane, out, grow0);  // b1_w1
  layer_g<4, 8, 0, 64, 64>(actb, wp +  24576, mbase, lane, out, grow0);  // b1_w2
  layer_g<4, 8, 0, 64, 64>(actb, wp +  40960, mbase, lane, out, grow0);  // b1_w3
  layer_g<4, 8, 0, 64, 64>(actb, wp +  57344, mbase, lane, out, grow0);  // b1_w4
  layer_g<6, 8, 0,  0, 64>(actb, wp +  73728, mbase, lane, out, grow0);  // b2_w0 (K=192)

  // posenc(dirs) -> cols 0..26, 27..63 = 0 (x_emb dead; own rows only)
  {
    float p0 = dirs[g * 3 + 0], p1 = dirs[g * 3 + 1], p2 = dirs[g * 3 + 2];
    if (lane < 32) posenc_store<0, 4>(actb, row, p0, p1, p2);
    else           posenc_store<32, 4>(actb, row, p0, p1, p2);   // all zeros
  }

  layer_g<4, 8, 0, 64, 64>(actb, wp +  98304, mbase, lane, out, grow0);  // b2_w1
  layer_g<4, 8, 0, 64, 64>(actb, wp + 114688, mbase, lane, out, grow0);  // b2_w2
  layer_g<4, 9, 1, 64, 64>(actb, wp + 131072, mbase, lane, out, grow0);  // b2_w3 + sigma
  layer_g<6, 4, 0,  0,  0>(actb, wp + 149504, mbase, lane, out, grow0);  // b3_w0 (K=192) -> cols 0..63
  layer_g<2, 1, 2,  0,  0>(actb, wp + 161792, mbase, lane, out, grow0);  // b3_w1 -> color
}

extern "C" void kernel_launch(void* const* d_in, const int* in_sizes, int n_in,
                              void* d_out, int out_size, void* d_ws, size_t ws_size,
                              hipStream_t stream)
{
  const float* pos  = (const float*)d_in[0];
  const float* dirs = (const float*)d_in[1];
  unsigned short* wpack = (unsigned short*)d_ws;   // 325,632 B used
  float* out = (float*)d_out;

  prepack_k<<<dim3(11, 12, 1), 256, 0, stream>>>(
      (const float*)d_in[2], (const float*)d_in[3], (const float*)d_in[4],
      (const float*)d_in[5], (const float*)d_in[6], (const float*)d_in[7],
      (const float*)d_in[8], (const float*)d_in[9], (const float*)d_in[10],
      (const float*)d_in[11], (const float*)d_in[12], wpack);

  nerf_fused<<<NTOT / MWG, BLK, 0, stream>>>(pos, dirs, wpack, out);
}